// Round 1
// baseline (221.582 us; speedup 1.0000x reference)
//
#include <hip/hip_runtime.h>
#include <math.h>

// Problem constants (match reference)
constexpr int B = 1024;
constexpr int S = 50;
constexpr int H = 64;
constexpr int V = 40000;

// ---------------------------------------------------------------------------
// Kernel 1: pure streaming zero of out[B*V] (163.84 MB).
// Fill-style: no LDS, no barriers, grid-stride float4 stores.
// The harness's own fillBuffer hits ~6.5 TB/s with exactly this shape.
// ---------------------------------------------------------------------------
__global__ __launch_bounds__(256) void rrd_zero_kernel(float4* __restrict__ out4)
{
    const size_t n4     = (size_t)B * V / 4;          // 10,240,000 float4s
    const size_t stride = (size_t)gridDim.x * 256;
    size_t i = (size_t)blockIdx.x * 256 + threadIdx.x;
    const float4 z = make_float4(0.f, 0.f, 0.f, 0.f);
    for (; i < n4; i += stride) out4[i] = z;
}

// ---------------------------------------------------------------------------
// Kernel 2: scores -> softmax -> scatter. One block per batch row, 4 waves.
//  - no row zeroing (kernel 1 did it; stream order makes it visible)
//  - no LDS staging of am: each am[b,s,:] row is read exactly once by exactly
//    one wave -> wave-uniform float4 global reads (L1/L2), LDS was overhead
//  - Ur row -> registers directly from global (16 KB, L2-hot for all blocks)
//  - softmax + scatter entirely in wave 0 registers (no probs array/barrier)
// ---------------------------------------------------------------------------
__global__ __launch_bounds__(256) void rrd_compute_kernel(
    const float* __restrict__ am,    // [B,S,H]
    const float* __restrict__ lm,    // [B,H]
    const int*   __restrict__ items, // [B,S] int32
    const float* __restrict__ Wr,    // [H,H]
    const float* __restrict__ Ur,    // [H,H]
    const float* __restrict__ Vw,    // [H]
    const float* __restrict__ Vb,    // [1]
    float* __restrict__ out)         // [B,V], already zeroed
{
    const int b    = blockIdx.x;
    const int tid  = threadIdx.x;
    const int lane = tid & 63;
    const int wave = tid >> 6;

    __shared__ float s_l[H];
    __shared__ float s_sc[S];

    // l[b,k] = <last_memory[b,:], Wr[k,:]>   (Wr is 16 KB, L2-hot)
    if (tid < H) {
        const float4* wr4 = reinterpret_cast<const float4*>(Wr + tid * H);
        const float4* l4  = reinterpret_cast<const float4*>(lm + (size_t)b * H);
        float acc = 0.f;
        #pragma unroll
        for (int i = 0; i < H / 4; ++i) {
            float4 w = wr4[i], x = l4[i];
            acc = fmaf(x.x, w.x, acc);
            acc = fmaf(x.y, w.y, acc);
            acc = fmaf(x.z, w.z, acc);
            acc = fmaf(x.w, w.w, acc);
        }
        s_l[tid] = acc;
    }

    // Ur row of this lane into registers (global, L2-hot, 16 float4 loads)
    float ur[H];
    {
        const float4* u4 = reinterpret_cast<const float4*>(Ur + lane * H);
        #pragma unroll
        for (int i = 0; i < H / 4; ++i) {
            float4 u = u4[i];
            ur[4 * i + 0] = u.x;
            ur[4 * i + 1] = u.y;
            ur[4 * i + 2] = u.z;
            ur[4 * i + 3] = u.w;
        }
    }
    const float vw = Vw[lane];
    __syncthreads();
    const float lk = s_l[lane];

    // scores: wave w handles s = w, w+4, ...  (wave-uniform am reads)
    for (int s = wave; s < S; s += 4) {
        const float4* a4 =
            reinterpret_cast<const float4*>(am + ((size_t)b * S + s) * H);
        float acc = lk;
        #pragma unroll
        for (int i = 0; i < H / 4; ++i) {
            float4 v = a4[i];
            acc = fmaf(v.x, ur[4 * i + 0], acc);
            acc = fmaf(v.y, ur[4 * i + 1], acc);
            acc = fmaf(v.z, ur[4 * i + 2], acc);
            acc = fmaf(v.w, ur[4 * i + 3], acc);
        }
        float t = tanhf(acc) * vw;
        #pragma unroll
        for (int off = 32; off; off >>= 1) t += __shfl_xor(t, off, 64);
        if (lane == 0) s_sc[s] = t + Vb[0];
    }
    __syncthreads();

    // softmax over S=50 + scatter, all inside wave 0 (registers only)
    if (wave == 0) {
        float x = (lane < S) ? s_sc[lane] : -INFINITY;
        float m = x;
        #pragma unroll
        for (int off = 32; off; off >>= 1) m = fmaxf(m, __shfl_xor(m, off, 64));
        float e = (lane < S) ? expf(x - m) : 0.f;
        float sum = e;
        #pragma unroll
        for (int off = 32; off; off >>= 1) sum += __shfl_xor(sum, off, 64);
        if (lane < S) {
            const int it = items[b * S + lane];
            atomicAdd(out + (size_t)b * V + it, e / sum);  // dups accumulate
        }
    }
}

extern "C" void kernel_launch(void* const* d_in, const int* in_sizes, int n_in,
                              void* d_out, int out_size, void* d_ws, size_t ws_size,
                              hipStream_t stream) {
    const float* am    = (const float*)d_in[0];  // all_memory [B,S,H]
    const float* lm    = (const float*)d_in[1];  // last_memory [B,H]
    const int*   items = (const int*)  d_in[2];  // seq_item [B,S]
    const float* Wr    = (const float*)d_in[3];  // [H,H]
    const float* Ur    = (const float*)d_in[4];  // [H,H]
    const float* Vw    = (const float*)d_in[5];  // [H]
    const float* Vb    = (const float*)d_in[6];  // scalar
    float* out = (float*)d_out;                  // [B,V] fp32

    rrd_zero_kernel<<<dim3(2048), dim3(256), 0, stream>>>(
        reinterpret_cast<float4*>(out));
    rrd_compute_kernel<<<dim3(B), dim3(256), 0, stream>>>(
        am, lm, items, Wr, Ur, Vw, Vb, out);
}

// Round 2
// 208.949 us; speedup vs baseline: 1.0605x; 1.0605x over previous
//
#include <hip/hip_runtime.h>
#include <math.h>

// Problem constants (match reference)
constexpr int B = 1024;
constexpr int S = 50;
constexpr int H = 64;
constexpr int V = 40000;
constexpr int NRMAX = 13;  // max s-rows per wave (waves 0,1: 13; waves 2,3: 12)

// ---------------------------------------------------------------------------
// Compute-only kernel: scores -> softmax -> scatter. One block per batch row,
// 4 waves. Zeroing is done by hipMemsetAsync (the harness's own fill kernel
// sustains 6.75 TB/s on this buffer; ours didn't — stop hand-rolling it).
//
// Structure (exactly ONE barrier):
//  - wave w self-stages ONLY its own am rows (s = w, w+4, ...) into its own
//    LDS region: coalesced 256B/wave loads, broadcast reads, no cross-wave
//    dependency -> no staging barrier.
//  - l[b,k] computed per-lane redundantly in every wave (64 FMAs, Wr L2-hot)
//    -> no s_l staging, no barrier.
//  - items prefetched at kernel start (hides scatter-index latency).
//  - __syncthreads() only before wave-0 softmax (s_sc visibility).
// ---------------------------------------------------------------------------
__global__ __launch_bounds__(256) void rrd_compute_v2(
    const float* __restrict__ am,    // [B,S,H]
    const float* __restrict__ lm,    // [B,H]
    const int*   __restrict__ items, // [B,S] int32
    const float* __restrict__ Wr,    // [H,H]
    const float* __restrict__ Ur,    // [H,H]
    const float* __restrict__ Vw,    // [H]
    const float* __restrict__ Vb,    // [1]
    float* __restrict__ out)         // [B,V], zeroed by memset
{
    const int b    = blockIdx.x;
    const int tid  = threadIdx.x;
    const int lane = tid & 63;
    const int wave = tid >> 6;
    const int nr   = (S - wave + 3) >> 2;   // rows this wave owns

    __shared__ float s_am[4][NRMAX * H];    // 4 x 3328 B, per-wave private
    __shared__ float s_sc[S];

    // ---- stage own rows (coalesced, no cross-wave deps, no barrier) ----
    {
        const float* base = am + ((size_t)b * S + wave) * H + lane;
        for (int r = 0; r < nr; ++r)
            s_am[wave][r * H + lane] = base[(size_t)r * 4 * H];
    }

    // ---- per-lane parameters (Ur/Wr are 16 KB each, L2-hot) ----
    float ur[H];
    {
        const float4* u4 = reinterpret_cast<const float4*>(Ur + lane * H);
        #pragma unroll
        for (int i = 0; i < H / 4; ++i) {
            float4 u = u4[i];
            ur[4 * i + 0] = u.x; ur[4 * i + 1] = u.y;
            ur[4 * i + 2] = u.z; ur[4 * i + 3] = u.w;
        }
    }
    float lk = 0.f;
    {
        const float4* w4 = reinterpret_cast<const float4*>(Wr + lane * H);
        const float4* l4 = reinterpret_cast<const float4*>(lm + (size_t)b * H);
        #pragma unroll
        for (int i = 0; i < H / 4; ++i) {
            float4 w = w4[i], x = l4[i];
            lk = fmaf(x.x, w.x, lk); lk = fmaf(x.y, w.y, lk);
            lk = fmaf(x.z, w.z, lk); lk = fmaf(x.w, w.w, lk);
        }
    }
    const float vw = Vw[lane];
    const float vb = Vb[0];
    const int my_item = (tid < S) ? items[b * S + tid] : 0;  // prefetch

    // ---- scores: lane k accumulates over h, shfl-reduce over k ----
    for (int r = 0; r < nr; ++r) {
        const float4* a4 = reinterpret_cast<const float4*>(&s_am[wave][r * H]);
        float acc = lk;
        #pragma unroll
        for (int i = 0; i < H / 4; ++i) {   // 16 broadcast ds_read_b128
            float4 v = a4[i];
            acc = fmaf(v.x, ur[4 * i + 0], acc);
            acc = fmaf(v.y, ur[4 * i + 1], acc);
            acc = fmaf(v.z, ur[4 * i + 2], acc);
            acc = fmaf(v.w, ur[4 * i + 3], acc);
        }
        float t = tanhf(acc) * vw;
        #pragma unroll
        for (int off = 32; off; off >>= 1) t += __shfl_xor(t, off, 64);
        if (lane == 0) s_sc[wave + 4 * r] = t + vb;
    }
    __syncthreads();   // the only barrier: publish s_sc to wave 0

    // ---- softmax over S=50 + scatter, wave 0 registers only ----
    if (wave == 0) {
        float x = (lane < S) ? s_sc[lane] : -INFINITY;
        float m = x;
        #pragma unroll
        for (int off = 32; off; off >>= 1) m = fmaxf(m, __shfl_xor(m, off, 64));
        float e = (lane < S) ? expf(x - m) : 0.f;
        float sum = e;
        #pragma unroll
        for (int off = 32; off; off >>= 1) sum += __shfl_xor(sum, off, 64);
        if (lane < S)
            atomicAdd(out + (size_t)b * V + my_item, e / sum);  // dups accumulate
    }
}

extern "C" void kernel_launch(void* const* d_in, const int* in_sizes, int n_in,
                              void* d_out, int out_size, void* d_ws, size_t ws_size,
                              hipStream_t stream) {
    const float* am    = (const float*)d_in[0];  // all_memory [B,S,H]
    const float* lm    = (const float*)d_in[1];  // last_memory [B,H]
    const int*   items = (const int*)  d_in[2];  // seq_item [B,S]
    const float* Wr    = (const float*)d_in[3];  // [H,H]
    const float* Ur    = (const float*)d_in[4];  // [H,H]
    const float* Vw    = (const float*)d_in[5];  // [H]
    const float* Vb    = (const float*)d_in[6];  // scalar
    float* out = (float*)d_out;                  // [B,V] fp32

    // Zero the output via the runtime's fill path (graph-capturable; the
    // harness's own reset() uses hipMemsetAsync). fillBufferAligned sustains
    // ~6.75 TB/s on this buffer -> ~24 us for 164 MB, by construction.
    hipMemsetAsync(d_out, 0, (size_t)B * V * sizeof(float), stream);

    rrd_compute_v2<<<dim3(B), dim3(256), 0, stream>>>(
        am, lm, items, Wr, Ur, Vw, Vb, out);
}

// Round 3
// 190.632 us; speedup vs baseline: 1.1624x; 1.0961x over previous
//
#include <hip/hip_runtime.h>
#include <math.h>

// Problem constants (match reference)
constexpr int B = 1024;
constexpr int S = 50;
constexpr int H = 64;
constexpr int V = 40000;

// ---------------------------------------------------------------------------
// Fused: zero own row + scores + softmax + scatter. One block per batch row.
// Restructured for latency:
//  - am staged as 800 coalesced float4 (fully unrolled -> all loads in
//    flight together, ONE cold-HBM latency exposure instead of 13 serial)
//  - Ur staged cooperatively (coalesced float4) into pad-65 LDS; per-lane
//    row reads are conflict-free. Kills the 64-distinct-cache-lines-per-
//    instruction global scatter the old per-lane loads caused.
//  - row-zero stores issued AFTER barrier 1, drained at barrier 2 -> the
//    164 MB store stream drains under the score-loop compute.
//  - exactly two barriers.
// ---------------------------------------------------------------------------
__global__ __launch_bounds__(256, 4) void rrd_fused_v3(
    const float* __restrict__ am,    // [B,S,H]
    const float* __restrict__ lm,    // [B,H]
    const int*   __restrict__ items, // [B,S] int32
    const float* __restrict__ Wr,    // [H,H]
    const float* __restrict__ Ur,    // [H,H]
    const float* __restrict__ Vw,    // [H]
    const float* __restrict__ Vb,    // [1]
    float* __restrict__ out)         // [B,V]
{
    const int b    = blockIdx.x;
    const int tid  = threadIdx.x;
    const int lane = tid & 63;
    const int wave = tid >> 6;

    __shared__ float s_am[S * H];      // 12.8 KB, linear
    __shared__ float s_Ur[H * 65];     // pad 65: row reads conflict-free
    __shared__ float s_l[H];
    __shared__ float s_sc[S];

    // ---- stage am: 800 coalesced float4, fully unrolled ----
    {
        const float4* src = reinterpret_cast<const float4*>(am + (size_t)b * S * H);
        float4*       dst = reinterpret_cast<float4*>(s_am);
        #pragma unroll
        for (int i = tid; i < S * H / 4; i += 256) dst[i] = src[i];
    }
    // ---- stage Ur: 1024 coalesced float4 -> padded LDS (4 scalar writes,
    //      2-way bank alias only = free) ----
    {
        const float4* src = reinterpret_cast<const float4*>(Ur);
        #pragma unroll
        for (int i = tid; i < H * H / 4; i += 256) {
            float4 u = src[i];
            const int r = (4 * i) >> 6, c = (4 * i) & 63;
            float* d = &s_Ur[r * 65 + c];
            d[0] = u.x; d[1] = u.y; d[2] = u.z; d[3] = u.w;
        }
    }
    // ---- l[k] = <lm[b,:], Wr[k,:]> (one wave; Wr is 16 KB, L2-hot) ----
    if (tid < H) {
        const float4* w4 = reinterpret_cast<const float4*>(Wr + tid * H);
        const float4* l4 = reinterpret_cast<const float4*>(lm + (size_t)b * H);
        float acc = 0.f;
        #pragma unroll
        for (int i = 0; i < H / 4; ++i) {
            float4 w = w4[i], x = l4[i];
            acc = fmaf(x.x, w.x, acc); acc = fmaf(x.y, w.y, acc);
            acc = fmaf(x.z, w.z, acc); acc = fmaf(x.w, w.w, acc);
        }
        s_l[tid] = acc;
    }
    const int   my_item = (tid < S) ? items[b * S + tid] : 0;  // prefetch
    const float vb      = Vb[0];
    const float vw      = Vw[lane];
    __syncthreads();   // barrier 1: staging + s_l visible (no stores yet)

    // ---- issue row-zero stores now; they drain under the score loop ----
    {
        float4* row4 = reinterpret_cast<float4*>(out + (size_t)b * V);
        const float4 z = make_float4(0.f, 0.f, 0.f, 0.f);
        #pragma unroll 10
        for (int i = tid; i < V / 4; i += 256) row4[i] = z;
    }

    // ---- per-lane Ur row from LDS (stride 65 -> conflict-free) ----
    float ur[H];
    #pragma unroll
    for (int h = 0; h < H; ++h) ur[h] = s_Ur[lane * 65 + h];
    const float lk = s_l[lane];

    // ---- scores: wave w handles s = w, w+4, ... (broadcast LDS reads) ----
    for (int s = wave; s < S; s += 4) {
        const float4* a4 = reinterpret_cast<const float4*>(s_am + s * H);
        float acc = lk;
        #pragma unroll
        for (int i = 0; i < H / 4; ++i) {
            float4 v = a4[i];
            acc = fmaf(v.x, ur[4 * i + 0], acc);
            acc = fmaf(v.y, ur[4 * i + 1], acc);
            acc = fmaf(v.z, ur[4 * i + 2], acc);
            acc = fmaf(v.w, ur[4 * i + 3], acc);
        }
        float t = tanhf(acc) * vw;
        #pragma unroll
        for (int off = 32; off; off >>= 1) t += __shfl_xor(t, off, 64);
        if (lane == 0) s_sc[s] = t + vb;
    }
    __syncthreads();   // barrier 2: s_sc visible; also drains zero stores

    // ---- softmax over S=50 + scatter (wave 0, registers only) ----
    if (wave == 0) {
        float x = (lane < S) ? s_sc[lane] : -INFINITY;
        float m = x;
        #pragma unroll
        for (int off = 32; off; off >>= 1) m = fmaxf(m, __shfl_xor(m, off, 64));
        float e = (lane < S) ? expf(x - m) : 0.f;
        float sum = e;
        #pragma unroll
        for (int off = 32; off; off >>= 1) sum += __shfl_xor(sum, off, 64);
        if (lane < S)
            atomicAdd(out + (size_t)b * V + my_item, e / sum);  // dups accumulate
    }
}

extern "C" void kernel_launch(void* const* d_in, const int* in_sizes, int n_in,
                              void* d_out, int out_size, void* d_ws, size_t ws_size,
                              hipStream_t stream) {
    const float* am    = (const float*)d_in[0];  // all_memory [B,S,H]
    const float* lm    = (const float*)d_in[1];  // last_memory [B,H]
    const int*   items = (const int*)  d_in[2];  // seq_item [B,S]
    const float* Wr    = (const float*)d_in[3];  // [H,H]
    const float* Ur    = (const float*)d_in[4];  // [H,H]
    const float* Vw    = (const float*)d_in[5];  // [H]
    const float* Vb    = (const float*)d_in[6];  // scalar
    float* out = (float*)d_out;                  // [B,V] fp32

    rrd_fused_v3<<<dim3(B), dim3(256), 0, stream>>>(
        am, lm, items, Wr, Ur, Vw, Vb, out);
}